// Round 2
// baseline (1393.143 us; speedup 1.0000x reference)
//
#include <hip/hip_runtime.h>
#include <hip/hip_bf16.h>

// ---------------------------------------------------------------------------
// AGNN: h = relu(x@W1^T+b1); 4x [ h = relu(agnn(h)) ]; out = h@W2^T+b2
// N=100000 nodes, E=1600000 edges, IN=128, HID=OUT=64. All float32 (per ref).
// edge_row sorted -> CSR via binary search. One wave64 per node, lane = dim.
// Online-softmax fused aggregation: single gather pass per layer.
// ---------------------------------------------------------------------------

__global__ __launch_bounds__(256) void build_rowptr(const int* __restrict__ row,
                                                    int* __restrict__ ptr,
                                                    int N, int E) {
    int i = blockIdx.x * blockDim.x + threadIdx.x;
    if (i > N) return;
    int lo = 0, hi = E;
    while (lo < hi) {
        int mid = (lo + hi) >> 1;
        if (row[mid] < i) lo = mid + 1; else hi = mid;
    }
    ptr[i] = lo;   // lower_bound(row, i); ptr[N] lands at E
}

// h[i,:] = relu(x[i,:] @ W1^T + b1), also inv[i] = 1/(||h_i||+1e-12)
__global__ __launch_bounds__(256) void gemm1_relu(const float* __restrict__ x,
                                                  const float* __restrict__ W1,
                                                  const float* __restrict__ b1,
                                                  float* __restrict__ h,
                                                  float* __restrict__ inv,
                                                  int N) {
    __shared__ float Wt[128 * 64];     // Wt[k*64+o] = W1[o*128+k]
    __shared__ float xrow[4][128];
    const int tid  = threadIdx.x;
    const int w    = tid >> 6;
    const int lane = tid & 63;
    const int i    = blockIdx.x * 4 + w;

    for (int idx = tid; idx < 128 * 64; idx += 256) {
        int o = idx & 63, k = idx >> 6;
        Wt[idx] = W1[o * 128 + k];
    }
    if (i < N) {
        xrow[w][lane]      = x[i * 128 + lane];
        xrow[w][lane + 64] = x[i * 128 + 64 + lane];
    }
    __syncthreads();
    if (i >= N) return;

    float acc = b1[lane];
#pragma unroll 8
    for (int k = 0; k < 128; ++k)
        acc = fmaf(xrow[w][k], Wt[k * 64 + lane], acc);

    float r = fmaxf(acc, 0.f);
    h[i * 64 + lane] = r;

    float s = r * r;
#pragma unroll
    for (int o = 32; o; o >>= 1) s += __shfl_xor(s, o, 64);
    if (lane == 0) inv[i] = 1.f / (sqrtf(s) + 1e-12f);
}

// One wave per destination node. Online softmax over its edge segment.
__global__ __launch_bounds__(256) void agnn_layer(const float* __restrict__ h,
                                                  const float* __restrict__ inv,
                                                  const int* __restrict__ ptr,
                                                  const int* __restrict__ col,
                                                  float* __restrict__ hn,
                                                  float* __restrict__ invn,
                                                  int N) {
    const int tid  = threadIdx.x;
    const int w    = tid >> 6;
    const int lane = tid & 63;
    const int i    = blockIdx.x * 4 + w;
    if (i >= N) return;

    const float hi    = h[i * 64 + lane];
    const float inv_i = inv[i];
    const int p0 = ptr[i], p1 = ptr[i + 1];

    float m = -INFINITY, denom = 0.f, acc = 0.f;
    for (int e = p0; e < p1; ++e) {
        const int j = col[e];
        const float hj = h[j * 64 + lane];
        float s = hi * hj;
#pragma unroll
        for (int o = 32; o; o >>= 1) s += __shfl_xor(s, o, 64);
        s *= inv_i * inv[j];

        const float mn = fmaxf(m, s);
        const float c  = __expf(m - mn);   // first iter: exp(-inf)=0
        const float p  = __expf(s - mn);
        denom = denom * c + p;
        acc   = fmaf(acc, c, p * hj);
        m = mn;
    }

    float o = fmaxf(acc / fmaxf(denom, 1e-12f), 0.f);   // relu(out)
    hn[i * 64 + lane] = o;

    float s2 = o * o;
#pragma unroll
    for (int off = 32; off; off >>= 1) s2 += __shfl_xor(s2, off, 64);
    if (lane == 0) invn[i] = 1.f / (sqrtf(s2) + 1e-12f);
}

// out[i,:] = h[i,:] @ W2^T + b2
__global__ __launch_bounds__(256) void gemm2(const float* __restrict__ h,
                                             const float* __restrict__ W2,
                                             const float* __restrict__ b2,
                                             float* __restrict__ out,
                                             int N) {
    __shared__ float Wt[64 * 64];      // Wt[k*64+o] = W2[o*64+k]
    __shared__ float xrow[4][64];
    const int tid  = threadIdx.x;
    const int w    = tid >> 6;
    const int lane = tid & 63;
    const int i    = blockIdx.x * 4 + w;

    for (int idx = tid; idx < 64 * 64; idx += 256) {
        int o = idx & 63, k = idx >> 6;
        Wt[idx] = W2[o * 64 + k];
    }
    if (i < N) xrow[w][lane] = h[i * 64 + lane];
    __syncthreads();
    if (i >= N) return;

    float acc = b2[lane];
#pragma unroll 8
    for (int k = 0; k < 64; ++k)
        acc = fmaf(xrow[w][k], Wt[k * 64 + lane], acc);

    out[i * 64 + lane] = acc;
}

extern "C" void kernel_launch(void* const* d_in, const int* in_sizes, int n_in,
                              void* d_out, int out_size, void* d_ws, size_t ws_size,
                              hipStream_t stream) {
    const float* x   = (const float*)d_in[0];
    const int*   row = (const int*)d_in[1];
    const int*   col = (const int*)d_in[2];
    const float* W1  = (const float*)d_in[3];
    const float* b1  = (const float*)d_in[4];
    const float* W2  = (const float*)d_in[5];
    const float* b2  = (const float*)d_in[6];
    float* out = (float*)d_out;

    const int N = in_sizes[0] / 128;
    const int E = in_sizes[1];

    char* ws = (char*)d_ws;
    size_t off = 0;
    float* ha   = (float*)(ws + off); off += (size_t)N * 64 * sizeof(float);
    float* hb   = (float*)(ws + off); off += (size_t)N * 64 * sizeof(float);
    float* inva = (float*)(ws + off); off += (size_t)N * sizeof(float);
    float* invb = (float*)(ws + off); off += (size_t)N * sizeof(float);
    int*   ptr  = (int*)  (ws + off); off += (size_t)(N + 1) * sizeof(int);
    (void)ws_size; (void)n_in; (void)out_size;

    build_rowptr<<<(N + 256) / 256, 256, 0, stream>>>(row, ptr, N, E);

    const int nb4 = (N + 3) / 4;
    gemm1_relu<<<nb4, 256, 0, stream>>>(x, W1, b1, ha, inva, N);

    float* hc = ha;  float* hn = hb;
    float* ic = inva; float* in2 = invb;
    for (int l = 0; l < 4; ++l) {
        agnn_layer<<<nb4, 256, 0, stream>>>(hc, ic, ptr, col, hn, in2, N);
        float* t;
        t = hc; hc = hn; hn = t;
        t = ic; ic = in2; in2 = t;
    }

    gemm2<<<nb4, 256, 0, stream>>>(hc, W2, b2, out, N);
}

// Round 3
// 472.096 us; speedup vs baseline: 2.9510x; 2.9510x over previous
//
#include <hip/hip_runtime.h>

// ---------------------------------------------------------------------------
// AGNN: h = relu(x@W1^T+b1); 4x [ h = relu(agnn(h)) ]; out = h@W2^T+b2
// N=100000, E=1600000, IN=128, HID=OUT=64, float32.
// gemm: 64 nodes/block, reg-tile 4o x 4m, 2x ds_read_b128 per 16 FMA.
// agnn: 1 wave/node, 4 edges in flight (16 lanes each), independent
//       online-softmax state per edge-group, merged once at the end.
// ---------------------------------------------------------------------------

#define DEV_INLINE __device__ __forceinline__

DEV_INLINE float dot4(float4 a, float4 b) {
    return fmaf(a.x, b.x, fmaf(a.y, b.y, fmaf(a.z, b.z, a.w * b.w)));
}

__global__ __launch_bounds__(256) void build_rowptr(const int* __restrict__ row,
                                                    int* __restrict__ ptr,
                                                    int N, int E) {
    int i = blockIdx.x * blockDim.x + threadIdx.x;
    if (i > N) return;
    int lo = 0, hi = E;
    while (lo < hi) {
        int mid = (lo + hi) >> 1;
        if (row[mid] < i) lo = mid + 1; else hi = mid;
    }
    ptr[i] = lo;
}

// C[i,o] = x[i,:K] @ W[o,:K] + b[o]; optional relu + inv-norm output.
// 64 nodes per block; thread (tx,ty): outputs 4tx..4tx+3, nodes 4ty..4ty+3.
template <int K, bool RN>
__global__ __launch_bounds__(256) void gemm_nodes(const float* __restrict__ x,
                                                  const float* __restrict__ W,
                                                  const float* __restrict__ bias,
                                                  float* __restrict__ h,
                                                  float* __restrict__ inv,
                                                  int N) {
    __shared__ __align__(16) float Wt[K * 64];   // Wt[k*64+o]
    __shared__ __align__(16) float xT[K * 64];   // xT[k*64+m]
    const int tid  = threadIdx.x;
    const int tx   = tid & 15;
    const int ty   = tid >> 4;
    const int base = blockIdx.x * 64;

    // stage W (lane-major over o -> LDS writes 2-way conflict-free)
    {
        const float4* W4 = (const float4*)W;
        for (int idx = tid; idx < K * 16; idx += 256) {
            int o = idx & 63, k4 = idx >> 6;
            float4 v = W4[o * (K / 4) + k4];
            Wt[(4 * k4 + 0) * 64 + o] = v.x;
            Wt[(4 * k4 + 1) * 64 + o] = v.y;
            Wt[(4 * k4 + 2) * 64 + o] = v.z;
            Wt[(4 * k4 + 3) * 64 + o] = v.w;
        }
        const float4* x4p = (const float4*)x;
        for (int idx = tid; idx < K * 16; idx += 256) {
            int mm = idx & 63, k4 = idx >> 6;
            int node = base + mm;
            float4 v = make_float4(0.f, 0.f, 0.f, 0.f);
            if (node < N) v = x4p[(size_t)node * (K / 4) + k4];
            xT[(4 * k4 + 0) * 64 + mm] = v.x;
            xT[(4 * k4 + 1) * 64 + mm] = v.y;
            xT[(4 * k4 + 2) * 64 + mm] = v.z;
            xT[(4 * k4 + 3) * 64 + mm] = v.w;
        }
    }
    __syncthreads();

    float4 b4 = ((const float4*)bias)[tx];
    float4 acc[4];
    acc[0] = b4; acc[1] = b4; acc[2] = b4; acc[3] = b4;

#pragma unroll 4
    for (int k = 0; k < K; ++k) {
        const float4 w4 = *(const float4*)&Wt[k * 64 + 4 * tx];
        const float4 xv = *(const float4*)&xT[k * 64 + 4 * ty];
        acc[0].x = fmaf(xv.x, w4.x, acc[0].x);
        acc[0].y = fmaf(xv.x, w4.y, acc[0].y);
        acc[0].z = fmaf(xv.x, w4.z, acc[0].z);
        acc[0].w = fmaf(xv.x, w4.w, acc[0].w);
        acc[1].x = fmaf(xv.y, w4.x, acc[1].x);
        acc[1].y = fmaf(xv.y, w4.y, acc[1].y);
        acc[1].z = fmaf(xv.y, w4.z, acc[1].z);
        acc[1].w = fmaf(xv.y, w4.w, acc[1].w);
        acc[2].x = fmaf(xv.z, w4.x, acc[2].x);
        acc[2].y = fmaf(xv.z, w4.y, acc[2].y);
        acc[2].z = fmaf(xv.z, w4.z, acc[2].z);
        acc[2].w = fmaf(xv.z, w4.w, acc[2].w);
        acc[3].x = fmaf(xv.w, w4.x, acc[3].x);
        acc[3].y = fmaf(xv.w, w4.y, acc[3].y);
        acc[3].z = fmaf(xv.w, w4.z, acc[3].z);
        acc[3].w = fmaf(xv.w, w4.w, acc[3].w);
    }

    float s2[4];
#pragma unroll
    for (int mm = 0; mm < 4; ++mm) {
        float4 r = acc[mm];
        if (RN) {
            r.x = fmaxf(r.x, 0.f); r.y = fmaxf(r.y, 0.f);
            r.z = fmaxf(r.z, 0.f); r.w = fmaxf(r.w, 0.f);
        }
        int node = base + 4 * ty + mm;
        if (node < N) *(float4*)&h[(size_t)node * 64 + 4 * tx] = r;
        if (RN) s2[mm] = dot4(r, r);
    }
    if (RN) {
#pragma unroll
        for (int mm = 0; mm < 4; ++mm) {
            float s = s2[mm];
            s += __shfl_xor(s, 1, 64);
            s += __shfl_xor(s, 2, 64);
            s += __shfl_xor(s, 4, 64);
            s += __shfl_xor(s, 8, 64);
            int node = base + 4 * ty + mm;
            if (tx == mm && node < N) inv[node] = 1.f / (sqrtf(s) + 1e-12f);
        }
    }
}

// One wave per node. 4 edges concurrently (16 lanes each, float4 dims).
__global__ __launch_bounds__(256) void agnn_layer(const float* __restrict__ h,
                                                  const float* __restrict__ inv,
                                                  const int* __restrict__ ptr,
                                                  const int* __restrict__ col,
                                                  float* __restrict__ hn,
                                                  float* __restrict__ invn,
                                                  int N) {
    const int tid  = threadIdx.x;
    const int w    = tid >> 6;
    const int lane = tid & 63;
    const int eg   = lane >> 4;   // edge group 0..3
    const int sub  = lane & 15;   // dim quad
    const int i    = blockIdx.x * 4 + w;
    if (i >= N) return;

    const float4* h4 = (const float4*)h;
    const float4 hi4  = h4[(size_t)i * 16 + sub];
    const float  ivi  = inv[i];
    const int p0 = ptr[i], p1 = ptr[i + 1];

    float  m   = -INFINITY;
    float  den = 0.f;
    float4 acc = make_float4(0.f, 0.f, 0.f, 0.f);

    for (int e = p0 + eg; e < p1; e += 4) {
        const int    j   = col[e];
        const float4 hj  = h4[(size_t)j * 16 + sub];
        const float  ivj = inv[j];
        float s = dot4(hi4, hj);
        s += __shfl_xor(s, 1, 64);
        s += __shfl_xor(s, 2, 64);
        s += __shfl_xor(s, 4, 64);
        s += __shfl_xor(s, 8, 64);
        s *= ivi * ivj;
        const float mn = fmaxf(m, s);
        const float c  = __expf(m - mn);   // first iter: exp(-inf)=0
        const float p  = __expf(s - mn);
        den = den * c + p;
        acc.x = fmaf(acc.x, c, p * hj.x);
        acc.y = fmaf(acc.y, c, p * hj.y);
        acc.z = fmaf(acc.z, c, p * hj.z);
        acc.w = fmaf(acc.w, c, p * hj.w);
        m = mn;
    }

    // merge the 4 per-group softmax states (xor 16, then 32), -inf-guarded
#pragma unroll
    for (int off = 16; off <= 32; off <<= 1) {
        const float  mo = __shfl_xor(m, off, 64);
        const float  dn = __shfl_xor(den, off, 64);
        float4 ao;
        ao.x = __shfl_xor(acc.x, off, 64);
        ao.y = __shfl_xor(acc.y, off, 64);
        ao.z = __shfl_xor(acc.z, off, 64);
        ao.w = __shfl_xor(acc.w, off, 64);
        const float mn = fmaxf(m, mo);
        const float sa = (m  > -INFINITY) ? __expf(m  - mn) : 0.f;
        const float sb = (mo > -INFINITY) ? __expf(mo - mn) : 0.f;
        den   = den * sa + dn * sb;
        acc.x = acc.x * sa + ao.x * sb;
        acc.y = acc.y * sa + ao.y * sb;
        acc.z = acc.z * sa + ao.z * sb;
        acc.w = acc.w * sa + ao.w * sb;
        m = mn;
    }

    const float id = 1.f / fmaxf(den, 1e-12f);
    float4 o4;
    o4.x = fmaxf(acc.x * id, 0.f);
    o4.y = fmaxf(acc.y * id, 0.f);
    o4.z = fmaxf(acc.z * id, 0.f);
    o4.w = fmaxf(acc.w * id, 0.f);
    if (eg == 0) ((float4*)hn)[(size_t)i * 16 + sub] = o4;

    float s2 = dot4(o4, o4);
    s2 += __shfl_xor(s2, 1, 64);
    s2 += __shfl_xor(s2, 2, 64);
    s2 += __shfl_xor(s2, 4, 64);
    s2 += __shfl_xor(s2, 8, 64);
    if (lane == 0) invn[i] = 1.f / (sqrtf(s2) + 1e-12f);
}

extern "C" void kernel_launch(void* const* d_in, const int* in_sizes, int n_in,
                              void* d_out, int out_size, void* d_ws, size_t ws_size,
                              hipStream_t stream) {
    const float* x   = (const float*)d_in[0];
    const int*   row = (const int*)d_in[1];
    const int*   col = (const int*)d_in[2];
    const float* W1  = (const float*)d_in[3];
    const float* b1  = (const float*)d_in[4];
    const float* W2  = (const float*)d_in[5];
    const float* b2  = (const float*)d_in[6];
    float* out = (float*)d_out;

    const int N = in_sizes[0] / 128;
    const int E = in_sizes[1];

    char* ws = (char*)d_ws;
    size_t off = 0;
    float* ha   = (float*)(ws + off); off += (size_t)N * 64 * sizeof(float);
    float* hb   = (float*)(ws + off); off += (size_t)N * 64 * sizeof(float);
    float* inva = (float*)(ws + off); off += (size_t)N * sizeof(float);
    float* invb = (float*)(ws + off); off += (size_t)N * sizeof(float);
    int*   ptr  = (int*)  (ws + off); off += (size_t)(N + 1) * sizeof(int);
    (void)ws_size; (void)n_in; (void)out_size;

    build_rowptr<<<(N + 256) / 256, 256, 0, stream>>>(row, ptr, N, E);

    const int nbG = (N + 63) / 64;
    gemm_nodes<128, true><<<nbG, 256, 0, stream>>>(x, W1, b1, ha, inva, N);

    const int nb4 = (N + 3) / 4;
    float* hc = ha;  float* hn = hb;
    float* ic = inva; float* in2 = invb;
    for (int l = 0; l < 4; ++l) {
        agnn_layer<<<nb4, 256, 0, stream>>>(hc, ic, ptr, col, hn, in2, N);
        float* t;
        t = hc; hc = hn; hn = t;
        t = ic; ic = in2; in2 = t;
    }

    gemm_nodes<64, false><<<nbG, 256, 0, stream>>>(hc, W2, b2, out, nullptr, N);
}

// Round 4
// 370.416 us; speedup vs baseline: 3.7610x; 1.2745x over previous
//
#include <hip/hip_runtime.h>

// ---------------------------------------------------------------------------
// AGNN: h = relu(x@W1^T+b1); 4x [ h = relu(agnn(h)) ]; out = h@W2^T+b2
// N=100000, E=1600000, IN=128, HID=OUT=64, float32 in/out.
// h stored bf16 (128 B/row) between layers; inv-norm f32.
// agnn: scores are cosines in [-1,1] -> exp(s) directly, no max subtraction
//       (softmax is shift-invariant; no overflow possible). 1 wave/node,
//       8 edges in flight (8 lanes x 16B = 8 bf16 dims per lane).
// ---------------------------------------------------------------------------

#define DEV_INLINE __device__ __forceinline__

DEV_INLINE void bf16x8_to_f32(const uint4 v, float f[8]) {
    f[0] = __uint_as_float(v.x << 16);
    f[1] = __uint_as_float(v.x & 0xffff0000u);
    f[2] = __uint_as_float(v.y << 16);
    f[3] = __uint_as_float(v.y & 0xffff0000u);
    f[4] = __uint_as_float(v.z << 16);
    f[5] = __uint_as_float(v.z & 0xffff0000u);
    f[6] = __uint_as_float(v.w << 16);
    f[7] = __uint_as_float(v.w & 0xffff0000u);
}

DEV_INLINE unsigned pack_bf16_2(float a, float b) {   // RNE, no NaN here
    unsigned ua = __float_as_uint(a); ua += 0x7fffu + ((ua >> 16) & 1u);
    unsigned ub = __float_as_uint(b); ub += 0x7fffu + ((ub >> 16) & 1u);
    return (ua >> 16) | (ub & 0xffff0000u);
}

__global__ __launch_bounds__(256) void build_rowptr(const int* __restrict__ row,
                                                    int* __restrict__ ptr,
                                                    int N, int E) {
    int i = blockIdx.x * blockDim.x + threadIdx.x;
    if (i > N) return;
    int lo = 0, hi = E;
    while (lo < hi) {
        int mid = (lo + hi) >> 1;
        if (row[mid] < i) lo = mid + 1; else hi = mid;
    }
    ptr[i] = lo;
}

// h_bf16[i,:64] = relu(x[i,:128] @ W1^T + b1); inv[i] = 1/(||h_i||+1e-12)
__global__ __launch_bounds__(256) void gemm1_relu(const float* __restrict__ x,
                                                  const float* __restrict__ W1,
                                                  const float* __restrict__ b1,
                                                  unsigned short* __restrict__ h,
                                                  float* __restrict__ inv,
                                                  int N) {
    __shared__ __align__(16) float Wt[128 * 64];   // Wt[k*64+o]
    __shared__ __align__(16) float xT[128 * 64];   // xT[k*64+m]
    const int tid  = threadIdx.x;
    const int tx   = tid & 15;
    const int ty   = tid >> 4;
    const int base = blockIdx.x * 64;

    {
        const float4* W4 = (const float4*)W1;
        for (int idx = tid; idx < 128 * 16; idx += 256) {
            int o = idx & 63, k4 = idx >> 6;
            float4 v = W4[o * 32 + k4];
            Wt[(4 * k4 + 0) * 64 + o] = v.x;
            Wt[(4 * k4 + 1) * 64 + o] = v.y;
            Wt[(4 * k4 + 2) * 64 + o] = v.z;
            Wt[(4 * k4 + 3) * 64 + o] = v.w;
        }
        const float4* x4p = (const float4*)x;
        for (int idx = tid; idx < 128 * 16; idx += 256) {
            int mm = idx & 63, k4 = idx >> 6;
            int node = base + mm;
            float4 v = make_float4(0.f, 0.f, 0.f, 0.f);
            if (node < N) v = x4p[(size_t)node * 32 + k4];
            xT[(4 * k4 + 0) * 64 + mm] = v.x;
            xT[(4 * k4 + 1) * 64 + mm] = v.y;
            xT[(4 * k4 + 2) * 64 + mm] = v.z;
            xT[(4 * k4 + 3) * 64 + mm] = v.w;
        }
    }
    __syncthreads();

    float4 b4 = ((const float4*)b1)[tx];
    float4 acc[4];
    acc[0] = b4; acc[1] = b4; acc[2] = b4; acc[3] = b4;

#pragma unroll 4
    for (int k = 0; k < 128; ++k) {
        const float4 w4 = *(const float4*)&Wt[k * 64 + 4 * tx];
        const float4 xv = *(const float4*)&xT[k * 64 + 4 * ty];
        acc[0].x = fmaf(xv.x, w4.x, acc[0].x);
        acc[0].y = fmaf(xv.x, w4.y, acc[0].y);
        acc[0].z = fmaf(xv.x, w4.z, acc[0].z);
        acc[0].w = fmaf(xv.x, w4.w, acc[0].w);
        acc[1].x = fmaf(xv.y, w4.x, acc[1].x);
        acc[1].y = fmaf(xv.y, w4.y, acc[1].y);
        acc[1].z = fmaf(xv.y, w4.z, acc[1].z);
        acc[1].w = fmaf(xv.y, w4.w, acc[1].w);
        acc[2].x = fmaf(xv.z, w4.x, acc[2].x);
        acc[2].y = fmaf(xv.z, w4.y, acc[2].y);
        acc[2].z = fmaf(xv.z, w4.z, acc[2].z);
        acc[2].w = fmaf(xv.z, w4.w, acc[2].w);
        acc[3].x = fmaf(xv.w, w4.x, acc[3].x);
        acc[3].y = fmaf(xv.w, w4.y, acc[3].y);
        acc[3].z = fmaf(xv.w, w4.z, acc[3].z);
        acc[3].w = fmaf(xv.w, w4.w, acc[3].w);
    }

    float s2[4];
#pragma unroll
    for (int mm = 0; mm < 4; ++mm) {
        float4 r = acc[mm];
        r.x = fmaxf(r.x, 0.f); r.y = fmaxf(r.y, 0.f);
        r.z = fmaxf(r.z, 0.f); r.w = fmaxf(r.w, 0.f);
        int node = base + 4 * ty + mm;
        if (node < N) {
            uint2 pk;
            pk.x = pack_bf16_2(r.x, r.y);
            pk.y = pack_bf16_2(r.z, r.w);
            *(uint2*)&h[(size_t)node * 64 + 4 * tx] = pk;
        }
        s2[mm] = fmaf(r.x, r.x, fmaf(r.y, r.y, fmaf(r.z, r.z, r.w * r.w)));
    }
#pragma unroll
    for (int mm = 0; mm < 4; ++mm) {
        float s = s2[mm];
        s += __shfl_xor(s, 1, 64);
        s += __shfl_xor(s, 2, 64);
        s += __shfl_xor(s, 4, 64);
        s += __shfl_xor(s, 8, 64);
        int node = base + 4 * ty + mm;
        if (tx == mm && node < N) inv[node] = 1.f / (sqrtf(s) + 1e-12f);
    }
}

// One wave per node; 8 edges concurrently (8 lanes each, 8 bf16 dims/lane).
__global__ __launch_bounds__(256) void agnn_layer(const uint4* __restrict__ h4,
                                                  const float* __restrict__ inv,
                                                  const int* __restrict__ ptr,
                                                  const int* __restrict__ col,
                                                  uint4* __restrict__ hn4,
                                                  float* __restrict__ invn,
                                                  int N) {
    const int tid  = threadIdx.x;
    const int w    = tid >> 6;
    const int lane = tid & 63;
    const int eg   = lane >> 3;   // edge group 0..7
    const int sub  = lane & 7;    // dim octet
    const int i    = blockIdx.x * 4 + w;
    if (i >= N) return;

    float hi[8];
    bf16x8_to_f32(h4[(size_t)i * 8 + sub], hi);
    const float ivi = inv[i];
    const int p0 = ptr[i], p1 = ptr[i + 1];

    float den = 0.f;
    float acc[8] = {0.f, 0.f, 0.f, 0.f, 0.f, 0.f, 0.f, 0.f};

    int e = p0 + eg;
    // unroll-by-2: independent iterations -> two gathers in flight
    for (; e + 8 < p1; e += 16) {
        const int j0 = col[e];
        const int j1 = col[e + 8];
        const uint4 v0 = h4[(size_t)j0 * 8 + sub];
        const uint4 v1 = h4[(size_t)j1 * 8 + sub];
        const float iv0 = inv[j0];
        const float iv1 = inv[j1];
        float hj0[8], hj1[8];
        bf16x8_to_f32(v0, hj0);
        bf16x8_to_f32(v1, hj1);
        float s0 = 0.f, s1 = 0.f;
#pragma unroll
        for (int t = 0; t < 8; ++t) s0 = fmaf(hi[t], hj0[t], s0);
#pragma unroll
        for (int t = 0; t < 8; ++t) s1 = fmaf(hi[t], hj1[t], s1);
        s0 += __shfl_xor(s0, 1, 64);
        s1 += __shfl_xor(s1, 1, 64);
        s0 += __shfl_xor(s0, 2, 64);
        s1 += __shfl_xor(s1, 2, 64);
        s0 += __shfl_xor(s0, 4, 64);
        s1 += __shfl_xor(s1, 4, 64);
        const float p0e = __expf(s0 * ivi * iv0);
        const float p1e = __expf(s1 * ivi * iv1);
        den += p0e + p1e;
#pragma unroll
        for (int t = 0; t < 8; ++t) acc[t] = fmaf(p0e, hj0[t], acc[t]);
#pragma unroll
        for (int t = 0; t < 8; ++t) acc[t] = fmaf(p1e, hj1[t], acc[t]);
    }
    if (e < p1) {
        const int j = col[e];
        const uint4 v = h4[(size_t)j * 8 + sub];
        const float ivj = inv[j];
        float hj[8];
        bf16x8_to_f32(v, hj);
        float s = 0.f;
#pragma unroll
        for (int t = 0; t < 8; ++t) s = fmaf(hi[t], hj[t], s);
        s += __shfl_xor(s, 1, 64);
        s += __shfl_xor(s, 2, 64);
        s += __shfl_xor(s, 4, 64);
        const float p = __expf(s * ivi * ivj);
        den += p;
#pragma unroll
        for (int t = 0; t < 8; ++t) acc[t] = fmaf(p, hj[t], acc[t]);
    }

    // merge the 8 edge-groups (plain sums — no max bookkeeping needed)
#pragma unroll
    for (int off = 8; off <= 32; off <<= 1) {
        den += __shfl_xor(den, off, 64);
#pragma unroll
        for (int t = 0; t < 8; ++t) acc[t] += __shfl_xor(acc[t], off, 64);
    }

    const float id = 1.f / fmaxf(den, 1e-12f);
    float o[8];
#pragma unroll
    for (int t = 0; t < 8; ++t) o[t] = fmaxf(acc[t] * id, 0.f);

    if (eg == 0) {
        uint4 ov;
        ov.x = pack_bf16_2(o[0], o[1]);
        ov.y = pack_bf16_2(o[2], o[3]);
        ov.z = pack_bf16_2(o[4], o[5]);
        ov.w = pack_bf16_2(o[6], o[7]);
        hn4[(size_t)i * 8 + sub] = ov;
    }

    float s2 = 0.f;
#pragma unroll
    for (int t = 0; t < 8; ++t) s2 = fmaf(o[t], o[t], s2);
    s2 += __shfl_xor(s2, 1, 64);
    s2 += __shfl_xor(s2, 2, 64);
    s2 += __shfl_xor(s2, 4, 64);
    if (lane == 0) invn[i] = 1.f / (sqrtf(s2) + 1e-12f);
}

// out[i,:64] = h_bf16[i,:64] @ W2^T + b2   (f32 out)
__global__ __launch_bounds__(256) void gemm2(const unsigned short* __restrict__ h,
                                             const float* __restrict__ W2,
                                             const float* __restrict__ b2,
                                             float* __restrict__ out,
                                             int N) {
    __shared__ __align__(16) float Wt[64 * 64];
    __shared__ __align__(16) float xT[64 * 64];
    const int tid  = threadIdx.x;
    const int tx   = tid & 15;
    const int ty   = tid >> 4;
    const int base = blockIdx.x * 64;

    {
        const float4* W4 = (const float4*)W2;
        for (int idx = tid; idx < 64 * 16; idx += 256) {
            int o = idx & 63, k4 = idx >> 6;
            float4 v = W4[o * 16 + k4];
            Wt[(4 * k4 + 0) * 64 + o] = v.x;
            Wt[(4 * k4 + 1) * 64 + o] = v.y;
            Wt[(4 * k4 + 2) * 64 + o] = v.z;
            Wt[(4 * k4 + 3) * 64 + o] = v.w;
        }
        const uint2* x2 = (const uint2*)h;
        for (int idx = tid; idx < 64 * 16; idx += 256) {
            int mm = idx & 63, k4 = idx >> 6;
            int node = base + mm;
            uint2 v = make_uint2(0u, 0u);
            if (node < N) v = x2[(size_t)node * 16 + k4];
            xT[(4 * k4 + 0) * 64 + mm] = __uint_as_float(v.x << 16);
            xT[(4 * k4 + 1) * 64 + mm] = __uint_as_float(v.x & 0xffff0000u);
            xT[(4 * k4 + 2) * 64 + mm] = __uint_as_float(v.y << 16);
            xT[(4 * k4 + 3) * 64 + mm] = __uint_as_float(v.y & 0xffff0000u);
        }
    }
    __syncthreads();

    float4 b4 = ((const float4*)b2)[tx];
    float4 acc[4];
    acc[0] = b4; acc[1] = b4; acc[2] = b4; acc[3] = b4;

#pragma unroll 4
    for (int k = 0; k < 64; ++k) {
        const float4 w4 = *(const float4*)&Wt[k * 64 + 4 * tx];
        const float4 xv = *(const float4*)&xT[k * 64 + 4 * ty];
        acc[0].x = fmaf(xv.x, w4.x, acc[0].x);
        acc[0].y = fmaf(xv.x, w4.y, acc[0].y);
        acc[0].z = fmaf(xv.x, w4.z, acc[0].z);
        acc[0].w = fmaf(xv.x, w4.w, acc[0].w);
        acc[1].x = fmaf(xv.y, w4.x, acc[1].x);
        acc[1].y = fmaf(xv.y, w4.y, acc[1].y);
        acc[1].z = fmaf(xv.y, w4.z, acc[1].z);
        acc[1].w = fmaf(xv.y, w4.w, acc[1].w);
        acc[2].x = fmaf(xv.z, w4.x, acc[2].x);
        acc[2].y = fmaf(xv.z, w4.y, acc[2].y);
        acc[2].z = fmaf(xv.z, w4.z, acc[2].z);
        acc[2].w = fmaf(xv.z, w4.w, acc[2].w);
        acc[3].x = fmaf(xv.w, w4.x, acc[3].x);
        acc[3].y = fmaf(xv.w, w4.y, acc[3].y);
        acc[3].z = fmaf(xv.w, w4.z, acc[3].z);
        acc[3].w = fmaf(xv.w, w4.w, acc[3].w);
    }

#pragma unroll
    for (int mm = 0; mm < 4; ++mm) {
        int node = base + 4 * ty + mm;
        if (node < N) *(float4*)&out[(size_t)node * 64 + 4 * tx] = acc[mm];
    }
}

extern "C" void kernel_launch(void* const* d_in, const int* in_sizes, int n_in,
                              void* d_out, int out_size, void* d_ws, size_t ws_size,
                              hipStream_t stream) {
    const float* x   = (const float*)d_in[0];
    const int*   row = (const int*)d_in[1];
    const int*   col = (const int*)d_in[2];
    const float* W1  = (const float*)d_in[3];
    const float* b1  = (const float*)d_in[4];
    const float* W2  = (const float*)d_in[5];
    const float* b2  = (const float*)d_in[6];
    float* out = (float*)d_out;

    const int N = in_sizes[0] / 128;
    const int E = in_sizes[1];

    char* ws = (char*)d_ws;
    size_t off = 0;
    unsigned short* ha = (unsigned short*)(ws + off); off += (size_t)N * 64 * 2;
    unsigned short* hb = (unsigned short*)(ws + off); off += (size_t)N * 64 * 2;
    float* inva = (float*)(ws + off); off += (size_t)N * sizeof(float);
    float* invb = (float*)(ws + off); off += (size_t)N * sizeof(float);
    int*   ptr  = (int*)  (ws + off); off += (size_t)(N + 1) * sizeof(int);
    (void)ws_size; (void)n_in; (void)out_size;

    build_rowptr<<<(N + 256) / 256, 256, 0, stream>>>(row, ptr, N, E);

    const int nbG = (N + 63) / 64;
    gemm1_relu<<<nbG, 256, 0, stream>>>(x, W1, b1, ha, inva, N);

    const int nb4 = (N + 3) / 4;
    unsigned short* hc = ha; unsigned short* hn = hb;
    float* ic = inva; float* in2 = invb;
    for (int l = 0; l < 4; ++l) {
        agnn_layer<<<nb4, 256, 0, stream>>>((const uint4*)hc, ic, ptr, col,
                                            (uint4*)hn, in2, N);
        unsigned short* t = hc; hc = hn; hn = t;
        float* tf = ic; ic = in2; in2 = tf;
    }

    gemm2<<<nbG, 256, 0, stream>>>(hc, W2, b2, out, N);
}

// Round 5
// 326.802 us; speedup vs baseline: 4.2630x; 1.1335x over previous
//
#include <hip/hip_runtime.h>

// ---------------------------------------------------------------------------
// AGNN: h = relu(x@W1^T+b1); 4x [ h = relu(agnn(h)) ]; out = h@W2^T+b2
// N=100000, E=1600000, IN=128, HID=OUT=64, float32 in/out.
// Between layers: xn = h/(||h||+eps) in bf16 (128 B/row) + nrm = ||h||+eps f32.
//   score  = xn_i . xn_j  (no per-edge inv muls)
//   aggreg = sum p * nrm_j * xn_j ;  p = exp2(dot(xn_i*log2e, xn_j))
// agnn: 2 nodes/wave (32 lanes each), 4 edge-groups x 8 lanes, float2 packed
// math (v_pk_fma_f32), 2-level group merge.
// ---------------------------------------------------------------------------

typedef float v2f __attribute__((ext_vector_type(2)));

#define DEV_INLINE __device__ __forceinline__

DEV_INLINE v2f bf2(unsigned u) {
    v2f r;
    r.x = __uint_as_float(u << 16);
    r.y = __uint_as_float(u & 0xffff0000u);
    return r;
}

DEV_INLINE unsigned pack_bf16_2(float a, float b) {   // RNE, no NaN here
    unsigned ua = __float_as_uint(a); ua += 0x7fffu + ((ua >> 16) & 1u);
    unsigned ub = __float_as_uint(b); ub += 0x7fffu + ((ub >> 16) & 1u);
    return (ua >> 16) | (ub & 0xffff0000u);
}

__global__ __launch_bounds__(256) void build_rowptr(const int* __restrict__ row,
                                                    int* __restrict__ ptr,
                                                    int N, int E) {
    int i = blockIdx.x * blockDim.x + threadIdx.x;
    if (i > N) return;
    int lo = 0, hi = E;
    while (lo < hi) {
        int mid = (lo + hi) >> 1;
        if (row[mid] < i) lo = mid + 1; else hi = mid;
    }
    ptr[i] = lo;
}

// r = relu(x[i,:128]@W1^T + b1); xn[i]=bf16(r/(||r||+eps)); nrm[i]=||r||+eps
__global__ __launch_bounds__(256) void gemm1_relu(const float* __restrict__ x,
                                                  const float* __restrict__ W1,
                                                  const float* __restrict__ b1,
                                                  unsigned short* __restrict__ xn,
                                                  float* __restrict__ nrm,
                                                  int N) {
    __shared__ __align__(16) float Wt[128 * 64];   // Wt[k*64+o]
    __shared__ __align__(16) float xT[128 * 64];   // xT[k*64+m]
    const int tid  = threadIdx.x;
    const int tx   = tid & 15;
    const int ty   = tid >> 4;
    const int base = blockIdx.x * 64;

    {
        const float4* W4 = (const float4*)W1;
        for (int idx = tid; idx < 128 * 16; idx += 256) {
            int o = idx & 63, k4 = idx >> 6;
            float4 v = W4[o * 32 + k4];
            Wt[(4 * k4 + 0) * 64 + o] = v.x;
            Wt[(4 * k4 + 1) * 64 + o] = v.y;
            Wt[(4 * k4 + 2) * 64 + o] = v.z;
            Wt[(4 * k4 + 3) * 64 + o] = v.w;
        }
        const float4* x4p = (const float4*)x;
        for (int idx = tid; idx < 128 * 16; idx += 256) {
            int mm = idx & 63, k4 = idx >> 6;
            int node = base + mm;
            float4 v = make_float4(0.f, 0.f, 0.f, 0.f);
            if (node < N) v = x4p[(size_t)node * 32 + k4];
            xT[(4 * k4 + 0) * 64 + mm] = v.x;
            xT[(4 * k4 + 1) * 64 + mm] = v.y;
            xT[(4 * k4 + 2) * 64 + mm] = v.z;
            xT[(4 * k4 + 3) * 64 + mm] = v.w;
        }
    }
    __syncthreads();

    float4 b4 = ((const float4*)b1)[tx];
    float4 acc[4];
    acc[0] = b4; acc[1] = b4; acc[2] = b4; acc[3] = b4;

#pragma unroll 4
    for (int k = 0; k < 128; ++k) {
        const float4 w4 = *(const float4*)&Wt[k * 64 + 4 * tx];
        const float4 xv = *(const float4*)&xT[k * 64 + 4 * ty];
        acc[0].x = fmaf(xv.x, w4.x, acc[0].x);
        acc[0].y = fmaf(xv.x, w4.y, acc[0].y);
        acc[0].z = fmaf(xv.x, w4.z, acc[0].z);
        acc[0].w = fmaf(xv.x, w4.w, acc[0].w);
        acc[1].x = fmaf(xv.y, w4.x, acc[1].x);
        acc[1].y = fmaf(xv.y, w4.y, acc[1].y);
        acc[1].z = fmaf(xv.y, w4.z, acc[1].z);
        acc[1].w = fmaf(xv.y, w4.w, acc[1].w);
        acc[2].x = fmaf(xv.z, w4.x, acc[2].x);
        acc[2].y = fmaf(xv.z, w4.y, acc[2].y);
        acc[2].z = fmaf(xv.z, w4.z, acc[2].z);
        acc[2].w = fmaf(xv.z, w4.w, acc[2].w);
        acc[3].x = fmaf(xv.w, w4.x, acc[3].x);
        acc[3].y = fmaf(xv.w, w4.y, acc[3].y);
        acc[3].z = fmaf(xv.w, w4.z, acc[3].z);
        acc[3].w = fmaf(xv.w, w4.w, acc[3].w);
    }

#pragma unroll
    for (int mm = 0; mm < 4; ++mm) {
        float4 r = acc[mm];
        r.x = fmaxf(r.x, 0.f); r.y = fmaxf(r.y, 0.f);
        r.z = fmaxf(r.z, 0.f); r.w = fmaxf(r.w, 0.f);
        float s = fmaf(r.x, r.x, fmaf(r.y, r.y, fmaf(r.z, r.z, r.w * r.w)));
        s += __shfl_xor(s, 1, 64);
        s += __shfl_xor(s, 2, 64);
        s += __shfl_xor(s, 4, 64);
        s += __shfl_xor(s, 8, 64);               // butterfly: all tx have sum
        const float nn  = sqrtf(s) + 1e-12f;
        const float inv = 1.f / nn;
        int node = base + 4 * ty + mm;
        if (node < N) {
            uint2 pk;
            pk.x = pack_bf16_2(r.x * inv, r.y * inv);
            pk.y = pack_bf16_2(r.z * inv, r.w * inv);
            *(uint2*)&xn[(size_t)node * 64 + 4 * tx] = pk;
            if (tx == mm) nrm[node] = nn;
        }
    }
}

// 2 nodes per wave; 4 edge-groups x 8 lanes each; packed f32 math.
__global__ __launch_bounds__(256) void agnn_layer(const uint4* __restrict__ xn4,
                                                  const float* __restrict__ nrm,
                                                  const int* __restrict__ ptr,
                                                  const int* __restrict__ col,
                                                  uint4* __restrict__ xo4,
                                                  float* __restrict__ nrmo,
                                                  int N) {
    const int tid  = threadIdx.x;
    const int lane = tid & 63;
    const int g    = (lane >> 3) & 3;   // edge group 0..3 (within 32-lane half)
    const int sub  = lane & 7;          // 16B chunk of the 128B row
    const int i    = blockIdx.x * 8 + (tid >> 5);   // one node per 32-lane half
    if (i >= N) return;

    const float L2E = 1.4426950408889634f;
    const uint4 hv = xn4[(size_t)i * 8 + sub];
    v2f hi0 = bf2(hv.x), hi1 = bf2(hv.y), hi2v = bf2(hv.z), hi3 = bf2(hv.w);
    hi0 *= L2E; hi1 *= L2E; hi2v *= L2E; hi3 *= L2E;   // p = exp2(dot)

    const int p0 = ptr[i], p1 = ptr[i + 1];

    float den = 0.f;
    v2f a0 = {0.f, 0.f}, a1 = {0.f, 0.f}, a2 = {0.f, 0.f}, a3 = {0.f, 0.f};

    int e = p0 + g;
    for (; e + 4 < p1; e += 8) {             // 2 edges per group in flight
        const int ja = col[e];
        const int jb = col[e + 4];
        const uint4 va = xn4[(size_t)ja * 8 + sub];
        const uint4 vb = xn4[(size_t)jb * 8 + sub];
        const float na = nrm[ja];
        const float nb = nrm[jb];

        v2f x0 = bf2(va.x), x1 = bf2(va.y), x2 = bf2(va.z), x3 = bf2(va.w);
        v2f y0 = bf2(vb.x), y1 = bf2(vb.y), y2 = bf2(vb.z), y3 = bf2(vb.w);

        v2f sa2 = hi0 * x0; sa2 += hi1 * x1; sa2 += hi2v * x2; sa2 += hi3 * x3;
        v2f sb2 = hi0 * y0; sb2 += hi1 * y1; sb2 += hi2v * y2; sb2 += hi3 * y3;
        float sa = sa2.x + sa2.y;
        float sb = sb2.x + sb2.y;
        sa += __shfl_xor(sa, 1, 64);
        sb += __shfl_xor(sb, 1, 64);
        sa += __shfl_xor(sa, 2, 64);
        sb += __shfl_xor(sb, 2, 64);
        sa += __shfl_xor(sa, 4, 64);
        sb += __shfl_xor(sb, 4, 64);

        const float pa = exp2f(sa);
        const float pb = exp2f(sb);
        den += pa + pb;
        const float wa = pa * na;
        const float wb = pb * nb;
        v2f wa2 = {wa, wa}, wb2 = {wb, wb};
        a0 += wa2 * x0; a1 += wa2 * x1; a2 += wa2 * x2; a3 += wa2 * x3;
        a0 += wb2 * y0; a1 += wb2 * y1; a2 += wb2 * y2; a3 += wb2 * y3;
    }
    if (e < p1) {
        const int j = col[e];
        const uint4 v = xn4[(size_t)j * 8 + sub];
        const float nj = nrm[j];
        v2f x0 = bf2(v.x), x1 = bf2(v.y), x2 = bf2(v.z), x3 = bf2(v.w);
        v2f s2v = hi0 * x0; s2v += hi1 * x1; s2v += hi2v * x2; s2v += hi3 * x3;
        float s = s2v.x + s2v.y;
        s += __shfl_xor(s, 1, 64);
        s += __shfl_xor(s, 2, 64);
        s += __shfl_xor(s, 4, 64);
        const float p = exp2f(s);
        den += p;
        const float wp = p * nj;
        v2f w2 = {wp, wp};
        a0 += w2 * x0; a1 += w2 * x1; a2 += w2 * x2; a3 += w2 * x3;
    }

    // merge the 4 edge-groups (within the 32-lane half): xor 8, xor 16
#pragma unroll
    for (int off = 8; off <= 16; off <<= 1) {
        den  += __shfl_xor(den, off, 64);
        a0.x += __shfl_xor(a0.x, off, 64);  a0.y += __shfl_xor(a0.y, off, 64);
        a1.x += __shfl_xor(a1.x, off, 64);  a1.y += __shfl_xor(a1.y, off, 64);
        a2.x += __shfl_xor(a2.x, off, 64);  a2.y += __shfl_xor(a2.y, off, 64);
        a3.x += __shfl_xor(a3.x, off, 64);  a3.y += __shfl_xor(a3.y, off, 64);
    }

    const float id = 1.f / fmaxf(den, 1e-12f);
    float o[8];
    o[0] = fmaxf(a0.x * id, 0.f); o[1] = fmaxf(a0.y * id, 0.f);
    o[2] = fmaxf(a1.x * id, 0.f); o[3] = fmaxf(a1.y * id, 0.f);
    o[4] = fmaxf(a2.x * id, 0.f); o[5] = fmaxf(a2.y * id, 0.f);
    o[6] = fmaxf(a3.x * id, 0.f); o[7] = fmaxf(a3.y * id, 0.f);

    float s2 = 0.f;
#pragma unroll
    for (int t = 0; t < 8; ++t) s2 = fmaf(o[t], o[t], s2);
    s2 += __shfl_xor(s2, 1, 64);
    s2 += __shfl_xor(s2, 2, 64);
    s2 += __shfl_xor(s2, 4, 64);
    const float nn  = sqrtf(s2) + 1e-12f;
    const float inv = 1.f / nn;

    if (g == 0) {
        uint4 ov;
        ov.x = pack_bf16_2(o[0] * inv, o[1] * inv);
        ov.y = pack_bf16_2(o[2] * inv, o[3] * inv);
        ov.z = pack_bf16_2(o[4] * inv, o[5] * inv);
        ov.w = pack_bf16_2(o[6] * inv, o[7] * inv);
        xo4[(size_t)i * 8 + sub] = ov;
        if (sub == 0) nrmo[i] = nn;
    }
}

// out[i,:64] = (xn[i]*nrm[i]) @ W2^T + b2   (f32 out)
__global__ __launch_bounds__(256) void gemm2(const unsigned short* __restrict__ xn,
                                             const float* __restrict__ nrm,
                                             const float* __restrict__ W2,
                                             const float* __restrict__ b2,
                                             float* __restrict__ out,
                                             int N) {
    __shared__ __align__(16) float Wt[64 * 64];
    __shared__ __align__(16) float xT[64 * 64];
    const int tid  = threadIdx.x;
    const int tx   = tid & 15;
    const int ty   = tid >> 4;
    const int base = blockIdx.x * 64;

    {
        const float4* W4 = (const float4*)W2;
        for (int idx = tid; idx < 64 * 16; idx += 256) {
            int o = idx & 63, k4 = idx >> 6;
            float4 v = W4[o * 16 + k4];
            Wt[(4 * k4 + 0) * 64 + o] = v.x;
            Wt[(4 * k4 + 1) * 64 + o] = v.y;
            Wt[(4 * k4 + 2) * 64 + o] = v.z;
            Wt[(4 * k4 + 3) * 64 + o] = v.w;
        }
        const uint2* x2 = (const uint2*)xn;
        for (int idx = tid; idx < 64 * 16; idx += 256) {
            int mm = idx & 63, k4 = idx >> 6;
            int node = base + mm;
            uint2 v = make_uint2(0u, 0u);
            float nn = 0.f;
            if (node < N) { v = x2[(size_t)node * 16 + k4]; nn = nrm[node]; }
            xT[(4 * k4 + 0) * 64 + mm] = __uint_as_float(v.x << 16) * nn;
            xT[(4 * k4 + 1) * 64 + mm] = __uint_as_float(v.x & 0xffff0000u) * nn;
            xT[(4 * k4 + 2) * 64 + mm] = __uint_as_float(v.y << 16) * nn;
            xT[(4 * k4 + 3) * 64 + mm] = __uint_as_float(v.y & 0xffff0000u) * nn;
        }
    }
    __syncthreads();

    float4 b4 = ((const float4*)b2)[tx];
    float4 acc[4];
    acc[0] = b4; acc[1] = b4; acc[2] = b4; acc[3] = b4;

#pragma unroll 4
    for (int k = 0; k < 64; ++k) {
        const float4 w4 = *(const float4*)&Wt[k * 64 + 4 * tx];
        const float4 xv = *(const float4*)&xT[k * 64 + 4 * ty];
        acc[0].x = fmaf(xv.x, w4.x, acc[0].x);
        acc[0].y = fmaf(xv.x, w4.y, acc[0].y);
        acc[0].z = fmaf(xv.x, w4.z, acc[0].z);
        acc[0].w = fmaf(xv.x, w4.w, acc[0].w);
        acc[1].x = fmaf(xv.y, w4.x, acc[1].x);
        acc[1].y = fmaf(xv.y, w4.y, acc[1].y);
        acc[1].z = fmaf(xv.y, w4.z, acc[1].z);
        acc[1].w = fmaf(xv.y, w4.w, acc[1].w);
        acc[2].x = fmaf(xv.z, w4.x, acc[2].x);
        acc[2].y = fmaf(xv.z, w4.y, acc[2].y);
        acc[2].z = fmaf(xv.z, w4.z, acc[2].z);
        acc[2].w = fmaf(xv.z, w4.w, acc[2].w);
        acc[3].x = fmaf(xv.w, w4.x, acc[3].x);
        acc[3].y = fmaf(xv.w, w4.y, acc[3].y);
        acc[3].z = fmaf(xv.w, w4.z, acc[3].z);
        acc[3].w = fmaf(xv.w, w4.w, acc[3].w);
    }

#pragma unroll
    for (int mm = 0; mm < 4; ++mm) {
        int node = base + 4 * ty + mm;
        if (node < N) *(float4*)&out[(size_t)node * 64 + 4 * tx] = acc[mm];
    }
}

extern "C" void kernel_launch(void* const* d_in, const int* in_sizes, int n_in,
                              void* d_out, int out_size, void* d_ws, size_t ws_size,
                              hipStream_t stream) {
    const float* x   = (const float*)d_in[0];
    const int*   row = (const int*)d_in[1];
    const int*   col = (const int*)d_in[2];
    const float* W1  = (const float*)d_in[3];
    const float* b1  = (const float*)d_in[4];
    const float* W2  = (const float*)d_in[5];
    const float* b2  = (const float*)d_in[6];
    float* out = (float*)d_out;

    const int N = in_sizes[0] / 128;
    const int E = in_sizes[1];

    char* ws = (char*)d_ws;
    size_t off = 0;
    unsigned short* ha = (unsigned short*)(ws + off); off += (size_t)N * 64 * 2;
    unsigned short* hb = (unsigned short*)(ws + off); off += (size_t)N * 64 * 2;
    float* na_ = (float*)(ws + off); off += (size_t)N * sizeof(float);
    float* nb_ = (float*)(ws + off); off += (size_t)N * sizeof(float);
    int*   ptr = (int*)  (ws + off); off += (size_t)(N + 1) * sizeof(int);
    (void)ws_size; (void)n_in; (void)out_size;

    build_rowptr<<<(N + 256) / 256, 256, 0, stream>>>(row, ptr, N, E);

    const int nbG = (N + 63) / 64;
    gemm1_relu<<<nbG, 256, 0, stream>>>(x, W1, b1, ha, na_, N);

    const int nb8 = (N + 7) / 8;
    unsigned short* hc = ha; unsigned short* hn = hb;
    float* nc = na_; float* nn = nb_;
    for (int l = 0; l < 4; ++l) {
        agnn_layer<<<nb8, 256, 0, stream>>>((const uint4*)hc, nc, ptr, col,
                                            (uint4*)hn, nn, N);
        unsigned short* t = hc; hc = hn; hn = t;
        float* tf = nc; nc = nn; nn = tf;
    }

    gemm2<<<nbG, 256, 0, stream>>>(hc, nc, W2, b2, out, N);
}